// Round 1
// baseline (817.167 us; speedup 1.0000x reference)
//
#include <hip/hip_runtime.h>
#include <hip/hip_bf16.h>

#define DEVINL __device__ __forceinline__

typedef short bf16x4 __attribute__((ext_vector_type(4)));
typedef short bf16x8 __attribute__((ext_vector_type(8)));
typedef float f32x4 __attribute__((ext_vector_type(4)));
typedef unsigned short us4 __attribute__((ext_vector_type(4)));

// B=4, S=2048, D=1024, H=16, dh=64, 3D=3072. All tile shapes divide evenly.

DEVINL unsigned short f2bf(float f) {
  unsigned u = __builtin_bit_cast(unsigned, f);
  unsigned r = u + 0x7fffu + ((u >> 16) & 1u);
  return (unsigned short)(r >> 16);
}

DEVINL f32x4 mfma32(bf16x8 a, bf16x8 b, f32x4 c) {
  return __builtin_amdgcn_mfma_f32_16x16x32_bf16(a, b, c, 0, 0, 0);
}

DEVINL f32x4 mfma16(bf16x4 a, bf16x4 b, f32x4 c) {
#if __has_builtin(__builtin_amdgcn_mfma_f32_16x16x16bf16_1k)
  return __builtin_amdgcn_mfma_f32_16x16x16bf16_1k(a, b, c, 0, 0, 0);
#else
  asm volatile("v_mfma_f32_16x16x16_bf16 %0, %1, %2, %0"
               : "+v"(c) : "v"(a), "v"(b));
  return c;
#endif
}

#define GLOAD_LDS16(g, l)                                                    \
  __builtin_amdgcn_global_load_lds(                                          \
      (__attribute__((address_space(1))) void*)(unsigned short*)(g),         \
      (__attribute__((address_space(3))) void*)(l), 16, 0, 0)

// ---------------------------------------------------------------- convert
__global__ void cvtk(const float* __restrict__ src,
                     unsigned short* __restrict__ dst, int n4) {
  int i = blockIdx.x * 256 + threadIdx.x;
  const int st = gridDim.x * 256;
  for (; i < n4; i += st) {
    const float4 v = ((const float4*)src)[i];
    us4 o;
    o[0] = f2bf(v.x); o[1] = f2bf(v.y); o[2] = f2bf(v.z); o[3] = f2bf(v.w);
    ((us4*)dst)[i] = o;
  }
}

// ------------------------------------------------------------- QKV GEMM
// C[m][e] = sum_k X[m][k] * W[e][k];  M=8192, N=3072, K=1024
// epilogue scatters into Q[bh][s][64], K[bh][s][64], VT[bh][64][s]
__global__ __launch_bounds__(256, 2) void qkv_gemm(
    const unsigned short* __restrict__ A,    // [8192,1024]
    const unsigned short* __restrict__ Bw,   // [3072,1024]
    unsigned short* __restrict__ Qo,
    unsigned short* __restrict__ Ko,
    unsigned short* __restrict__ VTo) {
  constexpr int K = 1024, BK = 32;
  __shared__ unsigned short As[128 * BK];
  __shared__ unsigned short Bs[128 * BK];
  const int tid = threadIdx.x;
  const int lane = tid & 63;
  const int wid = tid >> 6;
  const int l15 = lane & 15, g = lane >> 4;
  const int m0 = blockIdx.y * 128;
  const int n0 = blockIdx.x * 128;
  const int wr = wid >> 1, wc = wid & 1;

  f32x4 acc[4][4] = {};

  const int sidx0 = tid * 8;
  const int sidx1 = (256 + tid) * 8;
  const int r0 = sidx0 >> 5, c0 = sidx0 & 31;
  const int r1 = sidx1 >> 5, c1 = sidx1 & 31;

  for (int k0 = 0; k0 < K; k0 += BK) {
    __syncthreads();
    GLOAD_LDS16(A + (size_t)(m0 + r0) * K + k0 + c0, As + sidx0);
    GLOAD_LDS16(Bw + (size_t)(n0 + r0) * K + k0 + c0, Bs + sidx0);
    GLOAD_LDS16(A + (size_t)(m0 + r1) * K + k0 + c1, As + sidx1);
    GLOAD_LDS16(Bw + (size_t)(n0 + r1) * K + k0 + c1, Bs + sidx1);
    __syncthreads();
    bf16x8 af[4], bfr[4];
#pragma unroll
    for (int i = 0; i < 4; ++i) {
      af[i] = *(const bf16x8*)(As + (wr * 64 + i * 16 + l15) * BK + g * 8);
      bfr[i] = *(const bf16x8*)(Bs + (wc * 64 + i * 16 + l15) * BK + g * 8);
    }
#pragma unroll
    for (int mi = 0; mi < 4; ++mi)
#pragma unroll
      for (int ni = 0; ni < 4; ++ni)
        acc[mi][ni] = mfma32(af[mi], bfr[ni], acc[mi][ni]);
  }

#pragma unroll
  for (int mi = 0; mi < 4; ++mi) {
    const int mbase = m0 + wr * 64 + mi * 16 + g * 4;
#pragma unroll
    for (int ni = 0; ni < 4; ++ni) {
      const int e = n0 + wc * 64 + ni * 16 + l15;
      const int h = e / 192;
      const int r = e - h * 192;
#pragma unroll
      for (int j = 0; j < 4; ++j) {
        const int mm = mbase + j;
        const int b = mm >> 11, s = mm & 2047;
        const int bh = b * 16 + h;
        const unsigned short v = f2bf(acc[mi][ni][j]);
        if (r < 64)
          Qo[((size_t)bh * 2048 + s) * 64 + r] = v;
        else if (r < 128)
          Ko[((size_t)bh * 2048 + s) * 64 + (r - 64)] = v;
        else
          VTo[((size_t)bh * 64 + (r - 128)) * 2048 + s] = v;
      }
    }
  }
}

// -------------------------------------------------------- flash attention
// one wave = 16 q rows of one (b,h); KV tile = 16.
// S^T = mfma(K_frag, Q_frag): col=q=lane&15, row=kv=(lane>>4)*4+j
// O^T = mfma16(VT_frag, P^T_frag): col=q=lane&15, row=dc=(lane>>4)*4+j
__global__ __launch_bounds__(256) void attn_fwd(
    const unsigned short* __restrict__ Q,
    const unsigned short* __restrict__ K,
    const unsigned short* __restrict__ VT,
    unsigned short* __restrict__ Vals) {
  const int tid = threadIdx.x;
  const int lane = tid & 63;
  const int wid = tid >> 6;
  const int l15 = lane & 15, g = lane >> 4;
  const int task = blockIdx.x * 4 + wid;  // 8192 tasks
  const int bh = task >> 7;
  const int q0 = (task & 127) << 4;
  const unsigned short* Qb = Q + (size_t)bh * (2048 * 64);
  const unsigned short* Kb = K + (size_t)bh * (2048 * 64);
  const unsigned short* Vb = VT + (size_t)bh * (64 * 2048);

  const bf16x8 qf0 = *(const bf16x8*)(Qb + (q0 + l15) * 64 + g * 8);
  const bf16x8 qf1 = *(const bf16x8*)(Qb + (q0 + l15) * 64 + 32 + g * 8);

  float m = -3.0e38f, lsum = 0.0f;
  f32x4 o[4] = {};

  for (int kv0 = 0; kv0 < 2048; kv0 += 16) {
    const bf16x8 kf0 = *(const bf16x8*)(Kb + (kv0 + l15) * 64 + g * 8);
    const bf16x8 kf1 = *(const bf16x8*)(Kb + (kv0 + l15) * 64 + 32 + g * 8);
    f32x4 s4 = {};
    s4 = mfma32(kf0, qf0, s4);
    s4 = mfma32(kf1, qf1, s4);

    float tm = fmaxf(fmaxf(s4[0], s4[1]), fmaxf(s4[2], s4[3]));
    tm = fmaxf(tm, __shfl_xor(tm, 16));
    tm = fmaxf(tm, __shfl_xor(tm, 32));
    const float mnew = fmaxf(m, tm);
    const float scale = __expf(m - mnew);
    const float p0 = __expf(s4[0] - mnew);
    const float p1 = __expf(s4[1] - mnew);
    const float p2 = __expf(s4[2] - mnew);
    const float p3 = __expf(s4[3] - mnew);
    float ps = (p0 + p1) + (p2 + p3);
    ps += __shfl_xor(ps, 16);
    ps += __shfl_xor(ps, 32);
    lsum = lsum * scale + ps;
    m = mnew;

    bf16x4 pf;
    pf[0] = (short)f2bf(p0);
    pf[1] = (short)f2bf(p1);
    pf[2] = (short)f2bf(p2);
    pf[3] = (short)f2bf(p3);

#pragma unroll
    for (int t = 0; t < 4; ++t) o[t] *= scale;
#pragma unroll
    for (int t = 0; t < 4; ++t) {
      const bf16x4 vf =
          *(const bf16x4*)(Vb + (t * 16 + l15) * 2048 + kv0 + g * 4);
      o[t] = mfma16(vf, pf, o[t]);
    }
  }

  const float inv = 1.0f / lsum;
  const int b = bh >> 4, h = bh & 15;
  unsigned short* outp = Vals + ((size_t)(b * 2048 + q0 + l15)) * 1024 + h * 64;
#pragma unroll
  for (int t = 0; t < 4; ++t) {
    us4 ov;
    ov[0] = f2bf(o[t][0] * inv);
    ov[1] = f2bf(o[t][1] * inv);
    ov[2] = f2bf(o[t][2] * inv);
    ov[3] = f2bf(o[t][3] * inv);
    *(us4*)(outp + t * 16 + g * 4) = ov;
  }
}

// ------------------------------------------------------------- out GEMM
// out[m][n] = sum_k vals[m][k] * Wout[n][k]; M=8192, N=1024, K=1024, fp32 out
__global__ __launch_bounds__(256, 2) void out_gemm(
    const unsigned short* __restrict__ A,    // [8192,1024]
    const unsigned short* __restrict__ Bw,   // [1024,1024]
    float* __restrict__ C) {
  constexpr int K = 1024, BK = 32;
  __shared__ unsigned short As[128 * BK];
  __shared__ unsigned short Bs[128 * BK];
  const int tid = threadIdx.x;
  const int lane = tid & 63;
  const int wid = tid >> 6;
  const int l15 = lane & 15, g = lane >> 4;
  const int m0 = blockIdx.y * 128;
  const int n0 = blockIdx.x * 128;
  const int wr = wid >> 1, wc = wid & 1;

  f32x4 acc[4][4] = {};

  const int sidx0 = tid * 8;
  const int sidx1 = (256 + tid) * 8;
  const int r0 = sidx0 >> 5, c0 = sidx0 & 31;
  const int r1 = sidx1 >> 5, c1 = sidx1 & 31;

  for (int k0 = 0; k0 < K; k0 += BK) {
    __syncthreads();
    GLOAD_LDS16(A + (size_t)(m0 + r0) * K + k0 + c0, As + sidx0);
    GLOAD_LDS16(Bw + (size_t)(n0 + r0) * K + k0 + c0, Bs + sidx0);
    GLOAD_LDS16(A + (size_t)(m0 + r1) * K + k0 + c1, As + sidx1);
    GLOAD_LDS16(Bw + (size_t)(n0 + r1) * K + k0 + c1, Bs + sidx1);
    __syncthreads();
    bf16x8 af[4], bfr[4];
#pragma unroll
    for (int i = 0; i < 4; ++i) {
      af[i] = *(const bf16x8*)(As + (wr * 64 + i * 16 + l15) * BK + g * 8);
      bfr[i] = *(const bf16x8*)(Bs + (wc * 64 + i * 16 + l15) * BK + g * 8);
    }
#pragma unroll
    for (int mi = 0; mi < 4; ++mi)
#pragma unroll
      for (int ni = 0; ni < 4; ++ni)
        acc[mi][ni] = mfma32(af[mi], bfr[ni], acc[mi][ni]);
  }

#pragma unroll
  for (int mi = 0; mi < 4; ++mi) {
    const int mbase = m0 + wr * 64 + mi * 16 + g * 4;
#pragma unroll
    for (int ni = 0; ni < 4; ++ni) {
      const int n = n0 + wc * 64 + ni * 16 + l15;
#pragma unroll
      for (int j = 0; j < 4; ++j)
        C[(size_t)(mbase + j) * 1024 + n] = acc[mi][ni][j];
    }
  }
}

// ---------------------------------------------------------------- launch
extern "C" void kernel_launch(void* const* d_in, const int* in_sizes, int n_in,
                              void* d_out, int out_size, void* d_ws,
                              size_t ws_size, hipStream_t stream) {
  const float* x = (const float*)d_in[0];      // [4,2048,1024]
  const float* w_qkv = (const float*)d_in[1];  // [3072,1024]
  const float* w_out = (const float*)d_in[2];  // [1024,1024]
  float* out = (float*)d_out;

  char* ws = (char*)d_ws;
  unsigned short* xb = (unsigned short*)(ws);                      // 16 MiB
  unsigned short* wqkvb = (unsigned short*)(ws + (16u << 20));     // 6 MiB
  unsigned short* woutb = (unsigned short*)(ws + (22u << 20));     // 2 MiB
  unsigned short* Qt = (unsigned short*)(ws + (24u << 20));        // 16 MiB
  unsigned short* Kt = (unsigned short*)(ws + (40u << 20));        // 16 MiB
  unsigned short* VTt = (unsigned short*)(ws + (56u << 20));       // 16 MiB
  unsigned short* vals = xb;  // reuse x's slot after qkv_gemm

  cvtk<<<2048, 256, 0, stream>>>(x, xb, 8388608 / 4);
  cvtk<<<2048, 256, 0, stream>>>(w_qkv, wqkvb, 3145728 / 4);
  cvtk<<<1024, 256, 0, stream>>>(w_out, woutb, 1048576 / 4);
  qkv_gemm<<<dim3(24, 64), 256, 0, stream>>>(xb, wqkvb, Qt, Kt, VTt);
  attn_fwd<<<2048, 256, 0, stream>>>(Qt, Kt, VTt, vals);
  out_gemm<<<dim3(8, 64), 256, 0, stream>>>(vals, woutb, out);
}

// Round 2
// 268.589 us; speedup vs baseline: 3.0424x; 3.0424x over previous
//
#include <hip/hip_runtime.h>
#include <hip/hip_bf16.h>

#define DEVINL __device__ __forceinline__

typedef short bf16x4 __attribute__((ext_vector_type(4)));
typedef short bf16x8 __attribute__((ext_vector_type(8)));
typedef float f32x4 __attribute__((ext_vector_type(4)));
typedef unsigned short us4 __attribute__((ext_vector_type(4)));

// B=4, S=2048, D=1024, H=16, dh=64, 3D=3072. All tile shapes divide evenly.

DEVINL unsigned short f2bf(float f) {
  unsigned u = __builtin_bit_cast(unsigned, f);
  unsigned r = u + 0x7fffu + ((u >> 16) & 1u);
  return (unsigned short)(r >> 16);
}

DEVINL f32x4 mfma32(bf16x8 a, bf16x8 b, f32x4 c) {
  return __builtin_amdgcn_mfma_f32_16x16x32_bf16(a, b, c, 0, 0, 0);
}

DEVINL f32x4 mfma16(bf16x4 a, bf16x4 b, f32x4 c) {
#if __has_builtin(__builtin_amdgcn_mfma_f32_16x16x16bf16_1k)
  return __builtin_amdgcn_mfma_f32_16x16x16bf16_1k(a, b, c, 0, 0, 0);
#else
  asm volatile("v_mfma_f32_16x16x16_bf16 %0, %1, %2, %0"
               : "+v"(c) : "v"(a), "v"(b));
  return c;
#endif
}

#define GLOAD_LDS16(g, l)                                                    \
  __builtin_amdgcn_global_load_lds(                                          \
      (__attribute__((address_space(1))) void*)(unsigned short*)(g),         \
      (__attribute__((address_space(3))) void*)(l), 16, 0, 0)

// ---------------------------------------------------------------- convert
__global__ void cvtk(const float* __restrict__ src,
                     unsigned short* __restrict__ dst, int n4) {
  int i = blockIdx.x * 256 + threadIdx.x;
  const int st = gridDim.x * 256;
  for (; i < n4; i += st) {
    const float4 v = ((const float4*)src)[i];
    us4 o;
    o[0] = f2bf(v.x); o[1] = f2bf(v.y); o[2] = f2bf(v.z); o[3] = f2bf(v.w);
    ((us4*)dst)[i] = o;
  }
}

// ------------------------------------------------------------- QKV GEMM
// C[m][e] = sum_k X[m][k] * W[e][k];  M=8192, N=3072, K=1024
// epilogue scatters into Q[bh][s][64], K[bh][s][64], VT[bh][64][s]
__global__ __launch_bounds__(256, 2) void qkv_gemm(
    const unsigned short* __restrict__ A,    // [8192,1024]
    const unsigned short* __restrict__ Bw,   // [3072,1024]
    unsigned short* __restrict__ Qo,
    unsigned short* __restrict__ Ko,
    unsigned short* __restrict__ VTo) {
  constexpr int K = 1024, BK = 32;
  __shared__ unsigned short As[128 * BK];
  __shared__ unsigned short Bs[128 * BK];
  const int tid = threadIdx.x;
  const int lane = tid & 63;
  const int wid = tid >> 6;
  const int l15 = lane & 15, g = lane >> 4;
  const int m0 = blockIdx.y * 128;
  const int n0 = blockIdx.x * 128;
  const int wr = wid >> 1, wc = wid & 1;

  f32x4 acc[4][4] = {};

  const int sidx0 = tid * 8;
  const int sidx1 = (256 + tid) * 8;
  const int r0 = sidx0 >> 5, c0 = sidx0 & 31;
  const int r1 = sidx1 >> 5, c1 = sidx1 & 31;

  for (int k0 = 0; k0 < K; k0 += BK) {
    __syncthreads();
    GLOAD_LDS16(A + (size_t)(m0 + r0) * K + k0 + c0, As + sidx0);
    GLOAD_LDS16(Bw + (size_t)(n0 + r0) * K + k0 + c0, Bs + sidx0);
    GLOAD_LDS16(A + (size_t)(m0 + r1) * K + k0 + c1, As + sidx1);
    GLOAD_LDS16(Bw + (size_t)(n0 + r1) * K + k0 + c1, Bs + sidx1);
    __syncthreads();
    bf16x8 af[4], bfr[4];
#pragma unroll
    for (int i = 0; i < 4; ++i) {
      af[i] = *(const bf16x8*)(As + (wr * 64 + i * 16 + l15) * BK + g * 8);
      bfr[i] = *(const bf16x8*)(Bs + (wc * 64 + i * 16 + l15) * BK + g * 8);
    }
#pragma unroll
    for (int mi = 0; mi < 4; ++mi)
#pragma unroll
      for (int ni = 0; ni < 4; ++ni)
        acc[mi][ni] = mfma32(af[mi], bfr[ni], acc[mi][ni]);
  }

#pragma unroll
  for (int mi = 0; mi < 4; ++mi) {
    const int mbase = m0 + wr * 64 + mi * 16 + g * 4;
#pragma unroll
    for (int ni = 0; ni < 4; ++ni) {
      const int e = n0 + wc * 64 + ni * 16 + l15;
      const int h = e / 192;
      const int r = e - h * 192;
#pragma unroll
      for (int j = 0; j < 4; ++j) {
        const int mm = mbase + j;
        const int b = mm >> 11, s = mm & 2047;
        const int bh = b * 16 + h;
        const unsigned short v = f2bf(acc[mi][ni][j]);
        if (r < 64)
          Qo[((size_t)bh * 2048 + s) * 64 + r] = v;
        else if (r < 128)
          Ko[((size_t)bh * 2048 + s) * 64 + (r - 64)] = v;
        else
          VTo[((size_t)bh * 64 + (r - 128)) * 2048 + s] = v;
      }
    }
  }
}

// -------------------------------------------------------- flash attention
// Block = 4 waves, each wave owns 16 q rows of one (b,h). KVBLK=64, shared
// double-buffered LDS staging of K[64][64] and VT-slice[64][64], XOR-swizzle
// ((row&7)<<4) applied on the global SOURCE address (inverse) + on ds_read.
// S^T = mfma(K_frag, Q_frag): col=q=lane&15, row=kv=(lane>>4)*4+j
// O^T = mfma16(VT_frag, P^T_frag): col=q=lane&15, row=dc=(lane>>4)*4+j
__global__ __launch_bounds__(256) void attn_fwd(
    const unsigned short* __restrict__ Q,
    const unsigned short* __restrict__ K,
    const unsigned short* __restrict__ VT,
    unsigned short* __restrict__ Vals) {
  __shared__ unsigned short Ks[2][64 * 64];
  __shared__ unsigned short Vs[2][64 * 64];
  const int tid = threadIdx.x;
  const int lane = tid & 63;
  const int wid = tid >> 6;
  const int l15 = lane & 15, g = lane >> 4;
  const int bh = blockIdx.x >> 5;
  const int q0 = (blockIdx.x & 31) * 64 + wid * 16;
  const unsigned short* Qb = Q + (size_t)bh * (2048 * 64);
  const unsigned short* Kb = K + (size_t)bh * (2048 * 64);
  const unsigned short* Vb = VT + (size_t)bh * (64 * 2048);

  // staging geometry: wave w fills 16-B chunks [w*128, w*128+128) of each 8KB
  // tile; chunk i -> tile row i>>3, dest col-byte (i&7)<<4, source col-byte
  // pre-swizzled so that LDS[r][cb] = global[r][cb ^ ((r&7)<<4)].
  const int i0 = wid * 128 + lane;
  const int i1 = i0 + 64;
  const int rr0 = i0 >> 3, rr1 = i1 >> 3;
  const int scb0 = ((lane & 7) << 4) ^ ((rr0 & 7) << 4);
  const int scb1 = ((lane & 7) << 4) ^ ((rr1 & 7) << 4);

#define STAGE(kv0, nb)                                                        \
  {                                                                           \
    GLOAD_LDS16(Kb + (size_t)((kv0) + rr0) * 64 + (scb0 >> 1),                \
                &Ks[nb][i0 * 8]);                                             \
    GLOAD_LDS16(Kb + (size_t)((kv0) + rr1) * 64 + (scb1 >> 1),                \
                &Ks[nb][i1 * 8]);                                             \
    GLOAD_LDS16(Vb + (size_t)rr0 * 2048 + (kv0) + (scb0 >> 1),                \
                &Vs[nb][i0 * 8]);                                             \
    GLOAD_LDS16(Vb + (size_t)rr1 * 2048 + (kv0) + (scb1 >> 1),                \
                &Vs[nb][i1 * 8]);                                             \
  }

  const bf16x8 qf0 = *(const bf16x8*)(Qb + (size_t)(q0 + l15) * 64 + g * 8);
  const bf16x8 qf1 =
      *(const bf16x8*)(Qb + (size_t)(q0 + l15) * 64 + 32 + g * 8);

  float m = -3.0e38f, lsum = 0.0f;
  f32x4 o[4] = {};

  STAGE(0, 0);
  __syncthreads();

  for (int kv0 = 0; kv0 < 2048; kv0 += 64) {
    const int cur = (kv0 >> 6) & 1;
    if (kv0 + 64 < 2048) STAGE(kv0 + 64, cur ^ 1);

    // ---- QK^T over 4 kv-subtiles
    f32x4 s4[4];
    const char* kbase = (const char*)Ks[cur];
#pragma unroll
    for (int sub = 0; sub < 4; ++sub) {
      const int r = sub * 16 + l15;
      const int swz = (r & 7) << 4;
      const bf16x8 kf0 = *(const bf16x8*)(kbase + r * 128 + ((g * 16) ^ swz));
      const bf16x8 kf1 =
          *(const bf16x8*)(kbase + r * 128 + ((64 + g * 16) ^ swz));
      f32x4 t = {};
      t = mfma32(kf0, qf0, t);
      t = mfma32(kf1, qf1, t);
      s4[sub] = t;
    }

    // ---- online softmax over the 64-kv tile
    float tm = s4[0][0];
#pragma unroll
    for (int sub = 0; sub < 4; ++sub)
#pragma unroll
      for (int j = 0; j < 4; ++j) tm = fmaxf(tm, s4[sub][j]);
    tm = fmaxf(tm, __shfl_xor(tm, 16));
    tm = fmaxf(tm, __shfl_xor(tm, 32));
    const float mnew = fmaxf(m, tm);
    const float scale = __expf(m - mnew);
    float ps = 0.0f;
    bf16x4 pf[4];
#pragma unroll
    for (int sub = 0; sub < 4; ++sub) {
#pragma unroll
      for (int j = 0; j < 4; ++j) {
        const float p = __expf(s4[sub][j] - mnew);
        ps += p;
        pf[sub][j] = (short)f2bf(p);
      }
    }
    ps += __shfl_xor(ps, 16);
    ps += __shfl_xor(ps, 32);
    lsum = lsum * scale + ps;
    m = mnew;

#pragma unroll
    for (int t = 0; t < 4; ++t) o[t] *= scale;

    // ---- PV over 4 d-subtiles x 4 kv-subtiles
    const char* vbase = (const char*)Vs[cur];
#pragma unroll
    for (int tD = 0; tD < 4; ++tD) {
      const int rv = tD * 16 + l15;
      const int swz = (rv & 7) << 4;
#pragma unroll
      for (int sub = 0; sub < 4; ++sub) {
        const bf16x4 vf =
            *(const bf16x4*)(vbase + rv * 128 + ((sub * 32 + g * 8) ^ swz));
        o[tD] = mfma16(vf, pf[sub], o[tD]);
      }
    }
    __syncthreads();
  }
#undef STAGE

  const float inv = 1.0f / lsum;
  const int b = bh >> 4, h = bh & 15;
  unsigned short* outp = Vals + ((size_t)(b * 2048 + q0 + l15)) * 1024 + h * 64;
#pragma unroll
  for (int t = 0; t < 4; ++t) {
    us4 ov;
    ov[0] = f2bf(o[t][0] * inv);
    ov[1] = f2bf(o[t][1] * inv);
    ov[2] = f2bf(o[t][2] * inv);
    ov[3] = f2bf(o[t][3] * inv);
    *(us4*)(outp + t * 16 + g * 4) = ov;
  }
}

// ------------------------------------------------------------- out GEMM
// out[m][n] = sum_k vals[m][k] * Wout[n][k]; M=8192, N=1024, K=1024, fp32 out
__global__ __launch_bounds__(256, 2) void out_gemm(
    const unsigned short* __restrict__ A,    // [8192,1024]
    const unsigned short* __restrict__ Bw,   // [1024,1024]
    float* __restrict__ C) {
  constexpr int K = 1024, BK = 32;
  __shared__ unsigned short As[128 * BK];
  __shared__ unsigned short Bs[128 * BK];
  const int tid = threadIdx.x;
  const int lane = tid & 63;
  const int wid = tid >> 6;
  const int l15 = lane & 15, g = lane >> 4;
  const int m0 = blockIdx.y * 128;
  const int n0 = blockIdx.x * 128;
  const int wr = wid >> 1, wc = wid & 1;

  f32x4 acc[4][4] = {};

  const int sidx0 = tid * 8;
  const int sidx1 = (256 + tid) * 8;
  const int r0 = sidx0 >> 5, c0 = sidx0 & 31;
  const int r1 = sidx1 >> 5, c1 = sidx1 & 31;

  for (int k0 = 0; k0 < K; k0 += BK) {
    __syncthreads();
    GLOAD_LDS16(A + (size_t)(m0 + r0) * K + k0 + c0, As + sidx0);
    GLOAD_LDS16(Bw + (size_t)(n0 + r0) * K + k0 + c0, Bs + sidx0);
    GLOAD_LDS16(A + (size_t)(m0 + r1) * K + k0 + c1, As + sidx1);
    GLOAD_LDS16(Bw + (size_t)(n0 + r1) * K + k0 + c1, Bs + sidx1);
    __syncthreads();
    bf16x8 af[4], bfr[4];
#pragma unroll
    for (int i = 0; i < 4; ++i) {
      af[i] = *(const bf16x8*)(As + (wr * 64 + i * 16 + l15) * BK + g * 8);
      bfr[i] = *(const bf16x8*)(Bs + (wc * 64 + i * 16 + l15) * BK + g * 8);
    }
#pragma unroll
    for (int mi = 0; mi < 4; ++mi)
#pragma unroll
      for (int ni = 0; ni < 4; ++ni)
        acc[mi][ni] = mfma32(af[mi], bfr[ni], acc[mi][ni]);
  }

#pragma unroll
  for (int mi = 0; mi < 4; ++mi) {
    const int mbase = m0 + wr * 64 + mi * 16 + g * 4;
#pragma unroll
    for (int ni = 0; ni < 4; ++ni) {
      const int n = n0 + wc * 64 + ni * 16 + l15;
#pragma unroll
      for (int j = 0; j < 4; ++j)
        C[(size_t)(mbase + j) * 1024 + n] = acc[mi][ni][j];
    }
  }
}

// ---------------------------------------------------------------- launch
extern "C" void kernel_launch(void* const* d_in, const int* in_sizes, int n_in,
                              void* d_out, int out_size, void* d_ws,
                              size_t ws_size, hipStream_t stream) {
  const float* x = (const float*)d_in[0];      // [4,2048,1024]
  const float* w_qkv = (const float*)d_in[1];  // [3072,1024]
  const float* w_out = (const float*)d_in[2];  // [1024,1024]
  float* out = (float*)d_out;

  char* ws = (char*)d_ws;
  unsigned short* xb = (unsigned short*)(ws);                      // 16 MiB
  unsigned short* wqkvb = (unsigned short*)(ws + (16u << 20));     // 6 MiB
  unsigned short* woutb = (unsigned short*)(ws + (22u << 20));     // 2 MiB
  unsigned short* Qt = (unsigned short*)(ws + (24u << 20));        // 16 MiB
  unsigned short* Kt = (unsigned short*)(ws + (40u << 20));        // 16 MiB
  unsigned short* VTt = (unsigned short*)(ws + (56u << 20));       // 16 MiB
  unsigned short* vals = xb;  // reuse x's slot after qkv_gemm

  cvtk<<<2048, 256, 0, stream>>>(x, xb, 8388608 / 4);
  cvtk<<<2048, 256, 0, stream>>>(w_qkv, wqkvb, 3145728 / 4);
  cvtk<<<1024, 256, 0, stream>>>(w_out, woutb, 1048576 / 4);
  qkv_gemm<<<dim3(24, 64), 256, 0, stream>>>(xb, wqkvb, Qt, Kt, VTt);
  attn_fwd<<<2048, 256, 0, stream>>>(Qt, Kt, VTt, vals);
  out_gemm<<<dim3(8, 64), 256, 0, stream>>>(vals, woutb, out);
}